// Round 4
// baseline (230.238 us; speedup 1.0000x reference)
//
#include <hip/hip_runtime.h>

#define NH   8192
#define DIM  256
#define NTOT 16384
#define TILE 256
#define NB   64                   // NTOT / TILE
#define NTRI (NB * (NB + 1) / 2)  // 2080
#define TRIOFF(x) ((x) * (2 * NB + 1 - (x)) / 2)  // x*(129-x)/2

constexpr float GAMMA = 0.00390625f; // 1/256

using short8  = __attribute__((ext_vector_type(8))) short;
using short4v = __attribute__((ext_vector_type(4))) short;
using f32x16  = __attribute__((ext_vector_type(16))) float;

__device__ __forceinline__ unsigned short bf16_rne(float f) {
    unsigned u = __float_as_uint(f);
    u += 0x7FFFu + ((u >> 16) & 1u);
    return (unsigned short)(u >> 16);
}

// ---------------- fused split (fp32 -> bf16 hi/lo) + row norms ----------------
__global__ void prep_kernel(const float* __restrict__ zs,
                            const float* __restrict__ zt,
                            unsigned short* __restrict__ Zh,
                            unsigned short* __restrict__ Zl,
                            float* __restrict__ n2) {
    int w = threadIdx.x >> 6, l = threadIdx.x & 63;
    int row = blockIdx.x * 4 + w;
    const float* zp = (row < NH) ? zs + (size_t)row * DIM
                                 : zt + (size_t)(row - NH) * DIM;
    float4 v = *(const float4*)(zp + l * 4);
    float s = v.x * v.x + v.y * v.y + v.z * v.z + v.w * v.w;
#pragma unroll
    for (int off = 32; off; off >>= 1) s += __shfl_xor(s, off);
    if (l == 0) n2[row] = s;

    float x[4] = {v.x, v.y, v.z, v.w};
    short4v hv, lv;
#pragma unroll
    for (int j = 0; j < 4; ++j) {
        unsigned short h = bf16_rne(x[j]);
        float hf = __uint_as_float((unsigned)h << 16);
        hv[j] = (short)h;
        lv[j] = (short)bf16_rne(x[j] - hf);
    }
    *(short4v*)(Zh + (size_t)row * DIM + l * 4) = hv;
    *(short4v*)(Zl + (size_t)row * DIM + l * 4) = lv;
}

// ---------------- main: 256x256 tiles, 8 waves, 32x32x16 MFMA, dbuf LDS ----------------
__global__ __launch_bounds__(512, 2)
void mmd_mfma_kernel(const unsigned short* __restrict__ Zh,
                     const unsigned short* __restrict__ Zl,
                     const float* __restrict__ n2,
                     double* __restrict__ partial) {
    // 2 buffers x {Ah, Al, Bh, Bl} x 256 rows x 32 cols bf16 = 131072 B
    __shared__ __align__(16) unsigned short lds[2][4][8192];

    const int tid = threadIdx.x;
    const int w = tid >> 6, l = tid & 63;
    const int wr = w >> 2, wc = w & 3;   // 2 x 4 wave grid; wave owns 128x64
    const int fr2 = l & 31;              // fragment row/col within 32
    const int g2  = l >> 5;              // k-half 0..1

    // XCD-aware bijective swizzle (2080 % 8 == 0 -> chunked remap is exact)
    int t = ((int)blockIdx.x & 7) * (NTRI / 8) + ((int)blockIdx.x >> 3);

    // linear t -> upper-triangle (r, c), r <= c
    int r = (int)((129.0 - sqrt(129.0 * 129.0 - 8.0 * (double)t)) * 0.5);
    if (r < 0) r = 0;
    if (r > NB - 1) r = NB - 1;
    while (r < NB - 1 && TRIOFF(r + 1) <= t) ++r;
    while (r > 0 && TRIOFF(r) > t) --r;
    const int c = r + (t - TRIOFF(r));
    const int xbase = r * TILE, ybase = c * TILE;

    const unsigned short* gAh = Zh + (size_t)xbase * DIM;
    const unsigned short* gAl = Zl + (size_t)xbase * DIM;
    const unsigned short* gBh = Zh + (size_t)ybase * DIM;
    const unsigned short* gBl = Zl + (size_t)ybase * DIM;

    // swizzled 16B slot for fragment reads: logical slot s=ks*2+g2, s' = s ^ ((row>>1)&3)
    const int skey = (fr2 >> 1) & 3;
    // base offsets (shorts): + m*1024 / + n*1024 (32 rows x 32 shorts per fragment)
    int aoff[2], boff[2];
#pragma unroll
    for (int ks = 0; ks < 2; ++ks) {
        const int sp = (ks * 2 + g2) ^ skey;
        aoff[ks] = (wr * 128 + fr2) * 32 + sp * 8;
        boff[ks] = (wc * 64  + fr2) * 32 + sp * 8;
    }

    // staging geometry: thread covers 16B at linear offset q*8192 + tid*16 per array
    const int srow0 = tid >> 2;                            // row (q=0); q=1 adds 128
    const int sslot = (tid & 3) ^ ((srow0 >> 1) & 3);      // pre-swizzled source slot
    const int scol  = sslot * 8;                           // element col within chunk
    const unsigned dsto = (unsigned)tid * 8;               // shorts; + q*4096

    f32x16 acc[4][2];
#pragma unroll
    for (int m = 0; m < 4; ++m)
#pragma unroll
        for (int n = 0; n < 2; ++n)
#pragma unroll
            for (int e = 0; e < 16; ++e) acc[m][n][e] = 0.f;

#define STAGE(KC, P)                                                               \
    {                                                                              \
        _Pragma("unroll")                                                          \
        for (int q = 0; q < 2; ++q) {                                              \
            const int rw = q * 128 + srow0;                                        \
            const size_t go = (size_t)rw * DIM + (KC) + scol;                      \
            unsigned short* d0 = (unsigned short*)&lds[P][0][q * 4096 + dsto];     \
            unsigned short* d1 = (unsigned short*)&lds[P][1][q * 4096 + dsto];     \
            unsigned short* d2 = (unsigned short*)&lds[P][2][q * 4096 + dsto];     \
            unsigned short* d3 = (unsigned short*)&lds[P][3][q * 4096 + dsto];     \
            __builtin_amdgcn_global_load_lds(gAh + go, d0, 16, 0, 0);              \
            __builtin_amdgcn_global_load_lds(gAl + go, d1, 16, 0, 0);              \
            __builtin_amdgcn_global_load_lds(gBh + go, d2, 16, 0, 0);              \
            __builtin_amdgcn_global_load_lds(gBl + go, d3, 16, 0, 0);              \
        }                                                                          \
    }

    STAGE(0, 0);
    __syncthreads();

    for (int ch = 0; ch < 8; ++ch) {
        const int p = ch & 1;
        if (ch < 7) STAGE((ch + 1) * 32, p ^ 1);

        const unsigned short* A_h = lds[p][0];
        const unsigned short* A_l = lds[p][1];
        const unsigned short* B_h = lds[p][2];
        const unsigned short* B_l = lds[p][3];

        short8 bh[2][2], bl[2][2];  // [ks][n]
#pragma unroll
        for (int ks = 0; ks < 2; ++ks)
#pragma unroll
            for (int n = 0; n < 2; ++n) {
                bh[ks][n] = *(const short8*)&B_h[boff[ks] + n * 1024];
                bl[ks][n] = *(const short8*)&B_l[boff[ks] + n * 1024];
            }
        __builtin_amdgcn_s_setprio(1);
#pragma unroll
        for (int m = 0; m < 4; ++m) {
#pragma unroll
            for (int ks = 0; ks < 2; ++ks) {
                short8 ah = *(const short8*)&A_h[aoff[ks] + m * 1024];
                short8 al = *(const short8*)&A_l[aoff[ks] + m * 1024];
#pragma unroll
                for (int n = 0; n < 2; ++n) {
                    acc[m][n] = __builtin_amdgcn_mfma_f32_32x32x16_bf16(ah, bh[ks][n], acc[m][n], 0, 0, 0);
                    acc[m][n] = __builtin_amdgcn_mfma_f32_32x32x16_bf16(ah, bl[ks][n], acc[m][n], 0, 0, 0);
                    acc[m][n] = __builtin_amdgcn_mfma_f32_32x32x16_bf16(al, bh[ks][n], acc[m][n], 0, 0, 0);
                }
            }
        }
        __builtin_amdgcn_s_setprio(0);
        __syncthreads();  // reads of lds[p] done; stage writes to lds[p^1] drained
    }

    // epilogue: d2 = |x|^2 + |y|^2 - 2 x.y, exp, sum
    // 32x32 C/D layout (m74/m101): col = lane&31, row = (reg&3) + 8*(reg>>2) + 4*(lane>>5)
    float yn[2];
#pragma unroll
    for (int n = 0; n < 2; ++n) yn[n] = n2[ybase + wc * 64 + n * 32 + fr2];
    float fsum = 0.0f;
#pragma unroll
    for (int m = 0; m < 4; ++m) {
#pragma unroll
        for (int rq = 0; rq < 4; ++rq) {
            float4 xnv = *(const float4*)&n2[xbase + wr * 128 + m * 32 + rq * 8 + g2 * 4];
            float xa[4] = {xnv.x, xnv.y, xnv.z, xnv.w};
#pragma unroll
            for (int j = 0; j < 4; ++j) {
#pragma unroll
                for (int n = 0; n < 2; ++n) {
                    float d2 = xa[j] + yn[n] - 2.0f * acc[m][n][rq * 4 + j];
                    d2 = fmaxf(d2, 0.0f);
                    fsum += __expf(-GAMMA * d2);
                }
            }
        }
    }

#pragma unroll
    for (int off = 32; off; off >>= 1) fsum += __shfl_xor(fsum, off);

    double* wsum = (double*)&lds[0][0][0];  // LDS free after last chunk barrier
    if (l == 0) wsum[w] = (double)fsum;
    __syncthreads();
    if (tid == 0) {
        double tot = 0.0;
#pragma unroll
        for (int i = 0; i < 8; ++i) tot += wsum[i];
        double wgt = ((xbase < NH) == (ybase < NH)) ? 1.0 : -1.0;
        if (r != c) wgt *= 2.0; // off-diagonal tiles counted twice (symmetry)
        partial[blockIdx.x] = wgt * tot;
    }
}

// ---------------- final reduce ----------------
__global__ void reduce_partials_kernel(const double* __restrict__ partial,
                                       float* __restrict__ out) {
    __shared__ double ws[4];
    double s = 0.0;
    for (int i = threadIdx.x; i < NTRI; i += 256) s += partial[i];
#pragma unroll
    for (int off = 32; off; off >>= 1) s += __shfl_xor(s, off);
    if ((threadIdx.x & 63) == 0) ws[threadIdx.x >> 6] = s;
    __syncthreads();
    if (threadIdx.x == 0) {
        double tot = ws[0] + ws[1] + ws[2] + ws[3];
        out[0] = (float)(tot / ((double)NH * (double)NH));
    }
}

extern "C" void kernel_launch(void* const* d_in, const int* in_sizes, int n_in,
                              void* d_out, int out_size, void* d_ws, size_t ws_size,
                              hipStream_t stream) {
    const float* zs = (const float*)d_in[0];
    const float* zt = (const float*)d_in[1];
    float* out = (float*)d_out;

    unsigned short* Zh = (unsigned short*)d_ws;                      // 8 MB
    unsigned short* Zl = (unsigned short*)((char*)d_ws + 8388608);   // 8 MB
    float*  n2      = (float*)((char*)d_ws + 16777216);              // 64 KB
    double* partial = (double*)((char*)d_ws + 16842752);             // 16.6 KB

    prep_kernel<<<NTOT / 4, 256, 0, stream>>>(zs, zt, Zh, Zl, n2);
    mmd_mfma_kernel<<<NTRI, 512, 0, stream>>>(Zh, Zl, n2, partial);
    reduce_partials_kernel<<<1, 256, 0, stream>>>(partial, out);
}